// Round 2
// baseline (4599.808 us; speedup 1.0000x reference)
//
#include <hip/hip_runtime.h>
#include <hip/hip_bf16.h>
#include <cmath>

// ConstraintMoE: E=6 experts, D=1024, H=4096, OUT=4, BT=8192, all fp32 in/out.
// Strategy: cast to bf16, MFMA GEMMs (m97 128x128 structure), fp32 accumulate.
// R1: resubmit of the hand-verified baseline (R0/R1 benches never acquired a
// GPU). Structure: 128x128 tile, BK=32, 4 waves, global_load_lds width=16,
// 2-barrier K-loop -- the m97/m103 ref-checked pattern (~900 TF at this shape).

#define NE   6
#define ND   1024
#define NH   4096
#define NOUT 4
#define NBT  8192

typedef __attribute__((ext_vector_type(8))) __bf16 bf16x8;
typedef __attribute__((ext_vector_type(2))) __bf16 bf16x2;
typedef __attribute__((ext_vector_type(4))) float  f32x4;

__device__ __forceinline__ void gload_lds16(const void* g, void* l) {
  __builtin_amdgcn_global_load_lds((__attribute__((address_space(1))) void*)g,
                                   (__attribute__((address_space(3))) void*)l,
                                   16, 0, 0);
}

// ACT: 0=relu, 1=gelu(tanh approx, JAX default), 2=tanh, 3=silu
template<int ACT>
__device__ __forceinline__ float act_fn(float x) {
  if constexpr (ACT == 0) {
    return fmaxf(x, 0.0f);
  } else if constexpr (ACT == 1) {
    float x3 = x * x * x;
    return 0.5f * x * (1.0f + tanhf(0.7978845608028654f * (x + 0.044715f * x3)));
  } else if constexpr (ACT == 2) {
    return tanhf(x);
  } else {
    return x / (1.0f + expf(-x));
  }
}

// ---------------------------------------------------------------------------
// fp32 -> bf16 straight convert (h). 8 elems/thread, exact coverage.
__global__ __launch_bounds__(256) void convert_h_kernel(
    const float* __restrict__ in, __bf16* __restrict__ out) {
  size_t i = ((size_t)blockIdx.x * 256 + threadIdx.x) * 8;
  f32x4 v0 = *(const f32x4*)(in + i);
  f32x4 v1 = *(const f32x4*)(in + i + 4);
  bf16x8 o;
  o[0] = (__bf16)v0[0]; o[1] = (__bf16)v0[1]; o[2] = (__bf16)v0[2]; o[3] = (__bf16)v0[3];
  o[4] = (__bf16)v1[0]; o[5] = (__bf16)v1[1]; o[6] = (__bf16)v1[2]; o[7] = (__bf16)v1[3];
  *(bf16x8*)(out + i) = o;
}

// ---------------------------------------------------------------------------
// W [K][N] fp32 -> WT [N][K] bf16 (transpose + convert). 64x64 tile via LDS.
__global__ __launch_bounds__(256) void transpose_convert_kernel(
    const float* __restrict__ W, __bf16* __restrict__ WT, int K, int N) {
  __shared__ __bf16 tile[64][65];   // +1 pad: break power-of-2 stride (G4)
  const int t  = threadIdx.x;
  const int k0 = blockIdx.y * 64, n0 = blockIdx.x * 64;

  const int tn = t & 63, tk = t >> 6;
  const float* src = W + (size_t)(k0 + tk) * N + n0 + tn;
  #pragma unroll
  for (int i = 0; i < 16; ++i)
    tile[tk + i * 4][tn] = (__bf16)src[(size_t)i * 4 * N];
  __syncthreads();

  const int kp = t & 31, nb = t >> 5;
  __bf16* dst = WT + (size_t)(n0 + nb) * K + k0 + kp * 2;
  #pragma unroll
  for (int i = 0; i < 8; ++i) {
    bf16x2 v;
    v[0] = tile[kp * 2][nb + i * 8];
    v[1] = tile[kp * 2 + 1][nb + i * 8];
    *(bf16x2*)(dst + (size_t)i * 8 * K) = v;
  }
}

// ---------------------------------------------------------------------------
// C = A[M][K] @ Bt[N][K]^T. 128x128 tile, BK=32, 4 waves (2x2), 16x16x32 MFMA.
// MODE 0: out = bf16, act(acc+bias). MODE 1: out fp32 = acc+bias (beta=0).
// MODE 2: out fp32 += acc+bias (beta=1).
template<int ACT, int MODE>
__global__ __launch_bounds__(256) void gemm_bt_kernel(
    const __bf16* __restrict__ A, const __bf16* __restrict__ Bt,
    const float* __restrict__ bias,
    __bf16* __restrict__ outb, float* __restrict__ outf,
    int M, int N, int K) {
  __shared__ __align__(16) __bf16 a_sh[128 * 32];
  __shared__ __align__(16) __bf16 b_sh[128 * 32];

  const int t    = threadIdx.x;
  const int lane = t & 63, wid = t >> 6;
  const int wr   = wid >> 1, wc = wid & 1;
  const int bm0  = blockIdx.y * 128, bn0 = blockIdx.x * 128;

  // staging: global_load_lds dest = wave-uniform base + lane*16 (m104/m108).
  // wave wid base = wid*1024 B; thread t covers row t>>2, k-offset (t&3)*8.
  const int srow = t >> 2;            // 0..63
  const int sk8  = (t & 3) * 8;       // 0,8,16,24
  const __bf16* Ag = A  + (size_t)(bm0 + srow) * K + sk8;
  const __bf16* Bg = Bt + (size_t)(bn0 + srow) * K + sk8;
  __bf16* a_dst = a_sh + wid * 512;   // wave-uniform LDS base (elements)
  __bf16* b_dst = b_sh + wid * 512;

  // fragment reads: A row / B col = lane&15, k-half = (lane>>4)*8
  const int fr = lane & 15;
  const int kb = (lane >> 4) * 8;
  const __bf16* a_rd = a_sh + (wr * 64 + fr) * 32 + kb;
  const __bf16* b_rd = b_sh + (wc * 64 + fr) * 32 + kb;

  f32x4 acc[4][4] = {};

  for (int kt = 0; kt < K; kt += 32) {
    gload_lds16(Ag + kt,                  a_dst);
    gload_lds16(Ag + (size_t)64 * K + kt, a_dst + 2048);
    gload_lds16(Bg + kt,                  b_dst);
    gload_lds16(Bg + (size_t)64 * K + kt, b_dst + 2048);
    __syncthreads();   // drains vmcnt -> staged data visible to all waves

    bf16x8 af[4], bf_[4];
    #pragma unroll
    for (int i = 0; i < 4; ++i) af[i]  = *(const bf16x8*)(a_rd + i * 512);
    #pragma unroll
    for (int i = 0; i < 4; ++i) bf_[i] = *(const bf16x8*)(b_rd + i * 512);
    #pragma unroll
    for (int mi = 0; mi < 4; ++mi)
      #pragma unroll
      for (int ni = 0; ni < 4; ++ni)
        acc[mi][ni] = __builtin_amdgcn_mfma_f32_16x16x32_bf16(
            af[mi], bf_[ni], acc[mi][ni], 0, 0, 0);
    __syncthreads();   // all reads done before next-iter staging overwrites
  }

  // epilogue. C/D map (m89-verified): col = lane&15, row = (lane>>4)*4 + reg
  const int orow = wr * 64 + (lane >> 4) * 4;
  const int ocol = wc * 64 + fr;
  #pragma unroll
  for (int ni = 0; ni < 4; ++ni) {
    const int gc   = bn0 + ocol + ni * 16;
    const float bv = bias[gc];
    #pragma unroll
    for (int mi = 0; mi < 4; ++mi) {
      const int gr0 = bm0 + orow + mi * 16;
      #pragma unroll
      for (int r = 0; r < 4; ++r) {
        const size_t idx = (size_t)(gr0 + r) * N + gc;
        float v = acc[mi][ni][r] + bv;
        if constexpr (MODE == 0) {
          outb[idx] = (__bf16)act_fn<ACT>(v);
        } else {
          if constexpr (MODE == 2) v += outf[idx];
          outf[idx] = v;
        }
      }
    }
  }
}

// ---------------------------------------------------------------------------
// aux[row][0..3] = x2[row][:] @ Wc[:][0..3] + bc.  One wave per row.
__global__ __launch_bounds__(256) void aux_kernel(
    const __bf16* __restrict__ x2, const float* __restrict__ Wc,
    const float* __restrict__ bc, float* __restrict__ out) {
  const int lane = threadIdx.x & 63;
  const int row  = blockIdx.x * 4 + (threadIdx.x >> 6);
  const __bf16* xr = x2 + (size_t)row * NH;
  float a0 = 0.f, a1 = 0.f, a2 = 0.f, a3 = 0.f;
  #pragma unroll
  for (int it = 0; it < 8; ++it) {
    const int k = it * 512 + lane * 8;
    bf16x8 xv = *(const bf16x8*)(xr + k);
    #pragma unroll
    for (int j = 0; j < 8; ++j) {
      const float xf = (float)xv[j];
      f32x4 w = *(const f32x4*)(Wc + (size_t)(k + j) * 4);
      a0 += xf * w[0]; a1 += xf * w[1]; a2 += xf * w[2]; a3 += xf * w[3];
    }
  }
  #pragma unroll
  for (int off = 32; off > 0; off >>= 1) {
    a0 += __shfl_xor(a0, off); a1 += __shfl_xor(a1, off);
    a2 += __shfl_xor(a2, off); a3 += __shfl_xor(a3, off);
  }
  if (lane == 0) {
    f32x4 r; r[0] = a0 + bc[0]; r[1] = a1 + bc[1]; r[2] = a2 + bc[2]; r[3] = a3 + bc[3];
    *(f32x4*)(out + (size_t)row * 4) = r;
  }
}

// ---------------------------------------------------------------------------
static void launch_gemm_act(int act, const __bf16* A, const __bf16* Bt,
                            const float* bias, __bf16* out,
                            int M, int N, int K, hipStream_t s) {
  dim3 g(N / 128, M / 128), b(256);
  switch (act) {
    case 0:  gemm_bt_kernel<0,0><<<g,b,0,s>>>(A,Bt,bias,out,nullptr,M,N,K); break;
    case 1:  gemm_bt_kernel<1,0><<<g,b,0,s>>>(A,Bt,bias,out,nullptr,M,N,K); break;
    case 2:  gemm_bt_kernel<2,0><<<g,b,0,s>>>(A,Bt,bias,out,nullptr,M,N,K); break;
    default: gemm_bt_kernel<3,0><<<g,b,0,s>>>(A,Bt,bias,out,nullptr,M,N,K); break;
  }
}

static void launch_gemm_main(bool accum, const __bf16* A, const __bf16* Bt,
                             const float* bias, float* out,
                             int M, int N, int K, hipStream_t s) {
  dim3 g(N / 128, M / 128), b(256);
  if (accum) gemm_bt_kernel<0,2><<<g,b,0,s>>>(A,Bt,bias,nullptr,out,M,N,K);
  else       gemm_bt_kernel<0,1><<<g,b,0,s>>>(A,Bt,bias,nullptr,out,M,N,K);
}

extern "C" void kernel_launch(void* const* d_in, const int* in_sizes, int n_in,
                              void* d_out, int out_size, void* d_ws, size_t ws_size,
                              hipStream_t stream) {
  (void)in_sizes; (void)n_in; (void)out_size; (void)ws_size;
  const float* h  = (const float*)d_in[0];
  const float* W1 = (const float*)d_in[1];
  const float* b1 = (const float*)d_in[2];
  const float* W2 = (const float*)d_in[3];
  const float* b2 = (const float*)d_in[4];
  const float* Wm = (const float*)d_in[5];
  const float* bm = (const float*)d_in[6];
  const float* Wc = (const float*)d_in[7];
  const float* bc = (const float*)d_in[8];

  float* out_main = (float*)d_out;                       // [8192][1024] fp32
  float* out_aux  = out_main + (size_t)NBT * ND;         // [6][8192][4]  fp32

  // ws layout (bytes): hb | x1b | x2b | W1T | W2T | WmT  = ~192 MiB total
  char* ws = (char*)d_ws;
  __bf16* hb  = (__bf16*)(ws + 0);           // 16,777,216
  __bf16* x1b = (__bf16*)(ws + 16777216);    // 67,108,864
  __bf16* x2b = (__bf16*)(ws + 83886080);    // 67,108,864
  __bf16* W1T = (__bf16*)(ws + 150994944);   //  8,388,608
  __bf16* W2T = (__bf16*)(ws + 159383552);   // 33,554,432
  __bf16* WmT = (__bf16*)(ws + 192937984);   //  8,388,608

  convert_h_kernel<<<4096, 256, 0, stream>>>(h, hb);

  static const int acts[NE] = {0, 1, 2, 3, 0, 1};
  for (int e = 0; e < NE; ++e) {
    // x1 = act(h @ W1[e] + b1[e])   [8192,4096]
    transpose_convert_kernel<<<dim3(NH/64, ND/64), 256, 0, stream>>>(
        W1 + (size_t)e * ND * NH, W1T, ND, NH);
    launch_gemm_act(acts[e], hb, W1T, b1 + (size_t)e * NH, x1b, NBT, NH, ND, stream);

    // x2 = act(x1 @ W2[e] + b2[e])  [8192,4096]
    transpose_convert_kernel<<<dim3(NH/64, NH/64), 256, 0, stream>>>(
        W2 + (size_t)e * NH * NH, W2T, NH, NH);
    launch_gemm_act(acts[e], x1b, W2T, b2 + (size_t)e * NH, x2b, NBT, NH, NH, stream);

    // main (+)= x2 @ Wm[e] + bm[e]  [8192,1024] fp32 into d_out
    transpose_convert_kernel<<<dim3(ND/64, NH/64), 256, 0, stream>>>(
        Wm + (size_t)e * NH * ND, WmT, NH, ND);
    launch_gemm_main(e > 0, x2b, WmT, bm + (size_t)e * ND, out_main, NBT, ND, NH, stream);

    // aux[e] = x2 @ Wc[e] + bc[e]   [8192,4] fp32
    aux_kernel<<<NBT/4, 256, 0, stream>>>(
        x2b, Wc + (size_t)e * NH * NOUT, bc + (size_t)e * NOUT,
        out_aux + (size_t)e * NBT * NOUT);
  }
}